// Round 12
// baseline (305.537 us; speedup 1.0000x reference)
//
#include <hip/hip_runtime.h>
#include <hip/hip_bf16.h>
#include <math.h>

// Problem constants
#define BB 8
#define SS 512
#define DD 768
#define LL 200

typedef __attribute__((ext_vector_type(8))) short bf16x8;
typedef __attribute__((ext_vector_type(4))) float f32x4;

__device__ inline short f2bf(float f) {
    unsigned u = __builtin_bit_cast(unsigned, f);
    unsigned r = (u + 0x7FFFu + ((u >> 16) & 1u)) >> 16;
    return (short)r;
}
__device__ inline float bf2f(short s) {
    unsigned u = ((unsigned)(unsigned short)s) << 16;
    return __builtin_bit_cast(float, u);
}

// ---------------------------------------------------------------------------
// MFMA bf16 GEMM (R7/R11-verified structure, BK=64, register prefetch)
// ---------------------------------------------------------------------------
#define LDP2 72   // LDS row pitch in bf16 (144 B = 9*16B odd)

template<int EPI, bool TB>
__global__ __launch_bounds__(256) void mgemm_k(
    const short* __restrict__ A, int lda,
    const void* __restrict__ Bv, int ldb,
    const float* __restrict__ bias,
    const void* __restrict__ Bv2, const float* __restrict__ bias2, int nsplit,
    const void* __restrict__ Bv3, const float* __restrict__ bias3, int nsplit2,
    float* __restrict__ Cf, int ldc,
    short* __restrict__ Cb, int ldcb,
    short* __restrict__ Ct, int ldct, int nsplitT,
    int M, int N, int K)
{
    __shared__ __align__(16) short As[64 * LDP2];
    __shared__ __align__(16) short Bs[64 * LDP2];
    const int tid = threadIdx.x;
    const int bm = blockIdx.y * 64;
    const int bn = blockIdx.x * 64;
    int bnb = bn;
    if (!TB) {
        if (bn >= nsplit2)      { Bv = Bv3; bias = bias3; bnb = bn - nsplit2; }
        else if (bn >= nsplit)  { Bv = Bv2; bias = bias2; bnb = bn - nsplit; }
    }
    const int w = tid >> 6, lane = tid & 63, g = lane >> 4, ln = lane & 15;
    const int Kp = (K + 63) & ~63;
    const int nt = Kp >> 6;

    const int ar = tid >> 2, ac = tid & 3;
    const int bkk = tid >> 2, bc = tid & 3;

    f32x4 acc[4];
    #pragma unroll
    for (int i = 0; i < 4; ++i) acc[i] = (f32x4){0.f, 0.f, 0.f, 0.f};

    bf16x8 aR0 = {0,0,0,0,0,0,0,0}, aR1 = {0,0,0,0,0,0,0,0};
    bf16x8 bR0 = {0,0,0,0,0,0,0,0}, bR1 = {0,0,0,0,0,0,0,0};
    float  bF[16];
    #pragma unroll
    for (int j = 0; j < 16; ++j) bF[j] = 0.f;

    const int gmS = bm + ar;
    const bool aOk = (gmS < M);

    auto fetchA = [&](int k0) {
        if (aOk) {
            const short* p = A + (size_t)gmS * lda + k0 + ac * 16;
            aR0 = *(const bf16x8*)p;
            aR1 = *(const bf16x8*)(p + 8);
        }
    };
    auto fetchB = [&](int k0) {
        if (TB) {
            const short* Bt = (const short*)Bv;
            int gn = bn + ar;
            if (gn < N) {
                const short* p = Bt + (size_t)gn * ldb + k0 + ac * 16;
                bR0 = *(const bf16x8*)p;
                bR1 = *(const bf16x8*)(p + 8);
            }
        } else {
            const float* Bp = (const float*)Bv;
            int gk = k0 + bkk;
            int n0 = bnb + bc * 16;
            int gn0 = bn + bc * 16;
            if (gk < K) {
                const float* p = Bp + (size_t)gk * ldb + n0;
                if (gn0 + 16 <= N) {
                    #pragma unroll
                    for (int q = 0; q < 4; ++q) {
                        float4 x = *(const float4*)(p + q * 4);
                        bF[q*4+0]=x.x; bF[q*4+1]=x.y; bF[q*4+2]=x.z; bF[q*4+3]=x.w;
                    }
                } else {
                    #pragma unroll
                    for (int j = 0; j < 16; ++j) bF[j] = (gn0 + j < N) ? p[j] : 0.f;
                }
            } else {
                #pragma unroll
                for (int j = 0; j < 16; ++j) bF[j] = 0.f;
            }
        }
    };

    fetchA(0);
    fetchB(0);

    for (int t = 0; t < nt; ++t) {
        {
            short* pa = As + ar * LDP2 + ac * 16;
            *(bf16x8*)pa = aR0;
            *(bf16x8*)(pa + 8) = aR1;
        }
        if (TB) {
            short* pb = Bs + ar * LDP2 + ac * 16;
            *(bf16x8*)pb = bR0;
            *(bf16x8*)(pb + 8) = bR1;
        } else {
            #pragma unroll
            for (int j = 0; j < 16; ++j)
                Bs[(bc * 16 + j) * LDP2 + bkk] = f2bf(bF[j]);
        }
        __syncthreads();

        if (t + 1 < nt) {
            int k0 = (t + 1) << 6;
            fetchA(k0);
            fetchB(k0);
        }

        #pragma unroll
        for (int ks = 0; ks < 2; ++ks) {
            bf16x8 a = *(const bf16x8*)(As + (w * 16 + ln) * LDP2 + ks * 32 + g * 8);
            #pragma unroll
            for (int nb = 0; nb < 4; ++nb) {
                bf16x8 b = *(const bf16x8*)(Bs + (nb * 16 + ln) * LDP2 + ks * 32 + g * 8);
                acc[nb] = __builtin_amdgcn_mfma_f32_16x16x32_bf16(a, b, acc[nb], 0, 0, 0);
            }
        }
        __syncthreads();
    }

    #pragma unroll
    for (int nb = 0; nb < 4; ++nb) {
        int gn = bn + nb * 16 + ln;
        float bv = (bias && gn < N) ? bias[bnb + nb * 16 + ln] : 0.f;
        #pragma unroll
        for (int r = 0; r < 4; ++r) {
            int gm = bm + w * 16 + g * 4 + r;
            if (gm < M && gn < N) {
                float v = acc[nb][r] + bv;
                if (EPI == 1) v = (v >= 0.f) ? v : 0.2f * v;
                else if (EPI == 2) v = 1.f / (1.f + expf(-v));
                if (Cf) Cf[(size_t)gm * ldc + gn] = v;
                if (Cb) Cb[(size_t)gm * ldcb + gn] = f2bf(v);
                if (Ct && gn >= nsplitT)
                    Ct[(size_t)(gn - nsplitT) * ldct + gm] = f2bf(v);
            }
        }
    }
}

// ---------------------------------------------------------------------------
#define WP 168     // conv W pitch (336 B = 21*16B odd) -> conflict-free b128
#define TP 24      // winT pitch (48 B = 3*16B odd)
#define WTR 217
#define WROWS 208
#define APAD 256
#define BIGN (1 << 30)

__global__ void prep_k(const float* __restrict__ cw, const float* __restrict__ cb,
                       const float* __restrict__ adj,
                       short* __restrict__ wkg, short* __restrict__ adj_bf)
{
    int idx = blockIdx.x * blockDim.x + threadIdx.x;
    if (idx < WROWS * WP) {
        int o = idx / WP, kk = idx % WP;
        int kj = kk >> 4, ki = kk & 15;
        float v = 0.f;
        if (o < LL && kj < 9) {
            if (ki < 9) v = cw[o * 81 + ki * 9 + kj];
            else if (ki == 9 && kj == 0) v = cb[o];
        }
        wkg[idx] = f2bf(v);
        return;
    }
    idx -= WROWS * WP;
    if (idx < LL * APAD) {
        int r = idx / APAD, c = idx % APAD;
        adj_bf[idx] = f2bf(c < LL ? adj[r * LL + c] : 0.f);
    }
}

// fused colsum + rsqrt + normalized adjacency: An[i][j] = bf16(A[j,i]d_i d_j)
__global__ void ca_k(const float* __restrict__ A, short* __restrict__ An)
{
    int i = blockIdx.x;
    int j = threadIdx.x;
    float si = 0.f, sj = 0.f;
    for (int l = 0; l < LL; ++l) {
        si += A[l * LL + i];
        if (j < LL) sj += A[l * LL + j];
    }
    float di = (si > 0.f) ? (1.f / sqrtf(si)) : 0.f;
    float dj = (sj > 0.f) ? (1.f / sqrtf(sj)) : 0.f;
    float v = (j < LL) ? A[j * LL + i] * di * dj : 0.f;
    An[i * APAD + j] = f2bf(v);
}

// l1-normalize columns of X [L,D] over L, emit bf16
__global__ void l1n_k(const float* __restrict__ X, short* __restrict__ Xb)
{
    int c = threadIdx.x >> 5, r = threadIdx.x & 31;
    int col = blockIdx.x * 8 + c;
    float s = 0.f;
    for (int l = r; l < LL; l += 32) s += fabsf(X[l * DD + col]);
    #pragma unroll
    for (int off = 16; off > 0; off >>= 1) s += __shfl_xor(s, off, 64);
    float inv = 1.f / fmaxf(s, 1e-12f);
    for (int l = r; l < LL; l += 32)
        Xb[l * DD + col] = f2bf(X[l * DD + col] * inv);
}

// fused doc l1-norm: per-block denom (64 d-cols) + bf16 convert of same slice
__global__ void docnorm_k(const float* __restrict__ doc, short* __restrict__ docb)
{
    int dc = blockIdx.x, b = blockIdx.y;
    int dx = threadIdx.x & 63, sy = threadIdx.x >> 6;
    int d = dc * 64 + dx;
    const float* pp = doc + (size_t)b * SS * DD + d;
    float s = 0.f;
    for (int t = sy; t < SS; t += 4) s += fabsf(pp[(size_t)t * DD]);
    __shared__ float red[4][64];
    red[sy][dx] = s;
    __syncthreads();
    float dn = fmaxf(red[0][dx] + red[1][dx] + red[2][dx] + red[3][dx], 1e-12f);
    float inv = 1.f / dn;
    short* qq = docb + (size_t)b * SS * DD + d;
    for (int t = sy; t < SS; t += 4) qq[(size_t)t * DD] = f2bf(pp[(size_t)t * DD] * inv);
}

// ---------------------------------------------------------------------------
// Conv body: branch-free, fully static; NS strips at SOFF; j-outer/s-inner
// MFMA order -> NS independent accumulator chains interleave at throughput.
// ---------------------------------------------------------------------------
template<int NS, int SOFF>
__device__ __forceinline__ void conv_body(const short* __restrict__ Wk,
                                          const short* __restrict__ WT,
                                          int ln, int g, float& lm)
{
    bf16x8 Af[NS][5];
    #pragma unroll
    for (int s = 0; s < NS; ++s)
        #pragma unroll
        for (int j = 0; j < 5; ++j)
            Af[s][j] = *(const bf16x8*)(Wk + ((SOFF + s) * 16 + ln) * WP + j * 32 + g * 8);

    #pragma unroll 1
    for (int nt = 0; nt < 13; ++nt) {
        bf16x8 Bf[5];
        #pragma unroll
        for (int j = 0; j < 5; ++j)
            Bf[j] = *(const bf16x8*)(WT + (nt * 16 + ln + 2 * j + (g >> 1)) * TP + (g & 1) * 8);

        f32x4 acc[NS];
        #pragma unroll
        for (int s = 0; s < NS; ++s) acc[s] = (f32x4){0.f, 0.f, 0.f, 0.f};

        #pragma unroll
        for (int j = 0; j < 5; ++j)
            #pragma unroll
            for (int s = 0; s < NS; ++s)
                acc[s] = __builtin_amdgcn_mfma_f32_16x16x32_bf16(Af[s][j], Bf[j], acc[s], 0, 0, 0);

        bool colOK = (nt < 12) | (ln < 8);
        #pragma unroll
        for (int s = 0; s < NS; ++s) {
            float t = fmaxf(fmaxf(acc[s][0], acc[s][1]), fmaxf(acc[s][2], acc[s][3]));
            bool ok = colOK & ((SOFF + s < 12) | (g < 2));   // o<200, l<200
            lm = ok ? fmaxf(lm, t) : lm;
        }
    }
}

// Fused conv(9x9,200ch)+bias -> max(channel,width) -> tanh.
// 512 threads = 8 waves = 4 positions x 2 o-halves. bf16 wla input.
__global__ __launch_bounds__(512, 1) void conv_max_k(
    const short* __restrict__ wlab,  // [4096, 200] bf16
    const short* __restrict__ wkg,   // [208][WP] bf16
    float* __restrict__ gate)        // [4096]
{
    extern __shared__ short smem[];
    short* Wk   = smem;                       // 208*168
    short* winT = Wk + WROWS * WP;            // 4*217*24
    short* wbf  = winT + 4 * WTR * TP;        // 12*216
    __shared__ float wredf[8];

    const int blk = blockIdx.x;               // 1024
    const int b = blk >> 7;
    const int s0 = (blk & 127) << 2;
    const int tid = threadIdx.x;

    {
        const int4* src = (const int4*)wkg;
        int4* dst = (int4*)Wk;
        for (int i = tid; i < WROWS * WP / 8; i += 512) dst[i] = src[i];
    }
    // stage window rows s0-4..s0+7 (12), cols -4..211 (bf16 direct copy)
    for (int idx = tid; idx < 12 * 216; idx += 512) {
        int r = idx / 216, c = idx % 216;
        int sr = s0 - 4 + r, col = c - 4;
        short v = 0;
        if (sr >= 0 && sr < SS && col >= 0 && col < LL)
            v = wlab[((size_t)b * SS + sr) * LL + col];
        wbf[idx] = v;
    }
    __syncthreads();
    for (int idx = tid; idx < 4 * WTR; idx += 512) {
        int p = idx / WTR, r = idx % WTR;
        short vals[16];
        #pragma unroll
        for (int i = 0; i < 9; ++i) vals[i] = (r < 216) ? wbf[(p + i) * 216 + r] : (short)0;
        vals[9] = (short)0x3F80;   // 1.0 bias tap
        #pragma unroll
        for (int i = 10; i < 16; ++i) vals[i] = 0;
        short* dstp = winT + (p * WTR + r) * TP;
        *(bf16x8*)dstp = *(const bf16x8*)vals;
        *(bf16x8*)(dstp + 8) = *(const bf16x8*)(vals + 8);
    }
    __syncthreads();

    const int w = tid >> 6;
    const int p = w >> 1;
    const int h = w & 1;
    const int lane = tid & 63;
    const int g = lane >> 4;
    const int ln = lane & 15;
    const short* WT = winT + p * WTR * TP;

    float lm = -INFINITY;
    if (h == 0) conv_body<7, 0>(Wk, WT, ln, g, lm);
    else        conv_body<6, 7>(Wk, WT, ln, g, lm);

    #pragma unroll
    for (int off = 32; off > 0; off >>= 1)
        lm = fmaxf(lm, __shfl_xor(lm, off, 64));
    if (lane == 0) wredf[w] = lm;
    __syncthreads();
    if (tid < 4)
        gate[((size_t)b << 9) + s0 + tid] = tanhf(fmaxf(wredf[2 * tid], wredf[2 * tid + 1]));
}

// ---------------------------------------------------------------------------
// h_enc partials from bf16 doc_nb (h = sum gate*doc/denom = sum gate*doc_nb)
// ---------------------------------------------------------------------------
__global__ void henc_part_k(const short* __restrict__ doc_nb, const float* __restrict__ gate,
                            float* __restrict__ hpart)
{
    int dc = blockIdx.x, sc = blockIdx.y, b = blockIdx.z;
    int dx = threadIdx.x & 63, sy = threadIdx.x >> 6;
    int d = dc * 64 + dx;
    float s = 0.f;
    for (int t = sy; t < 64; t += 4) {
        int srow = sc * 64 + t;
        s = fmaf(bf2f(doc_nb[((size_t)b * SS + srow) * DD + d]), gate[b * SS + srow], s);
    }
    __shared__ float red[4][64];
    red[sy][dx] = s;
    __syncthreads();
    if (sy == 0)
        hpart[((size_t)b * 8 + sc) * DD + d] = red[0][dx] + red[1][dx] + red[2][dx] + red[3][dx];
}

__global__ void final2_k(const float* __restrict__ hpart,
                         const float* __restrict__ W, const float* __restrict__ bias,
                         float* __restrict__ out)
{
    int b = blockIdx.x, tid = threadIdx.x;
    __shared__ float hb[DD];
    for (int idx = tid; idx < DD; idx += 256) {
        float s = 0.f;
        #pragma unroll
        for (int sc = 0; sc < 8; ++sc) s += hpart[((size_t)b * 8 + sc) * DD + idx];
        hb[idx] = s;
    }
    __syncthreads();
    int l = tid;
    if (l < LL) {
        float acc = bias[l];
        for (int d = 0; d < DD; ++d) acc = fmaf(hb[d], W[d * LL + l], acc);
        out[b * LL + l] = 1.f / (1.f + expf(-acc));
    }
}

__global__ void loss_k(const float* __restrict__ out, const float* __restrict__ labels,
                       float* __restrict__ loss_out)
{
    float s = 0.f;
    for (int i = threadIdx.x; i < BB * LL; i += 256) {
        float p = out[i];
        p = fminf(fmaxf(p, 1e-7f), 1.f - 1e-7f);
        float y = labels[i];
        s += y * logf(p) + (1.f - y) * logf(1.f - p);
    }
    #pragma unroll
    for (int off = 32; off > 0; off >>= 1) s += __shfl_down(s, off, 64);
    __shared__ float ws[4];
    if ((threadIdx.x & 63) == 0) ws[threadIdx.x >> 6] = s;
    __syncthreads();
    if (threadIdx.x == 0)
        loss_out[0] = -(ws[0] + ws[1] + ws[2] + ws[3]) / (float)(BB * LL);
}

// ---------------------------------------------------------------------------
static void mgemm(hipStream_t st, int epi, bool tb,
                  const short* A, int lda, const void* B, int ldb,
                  const float* bias,
                  const void* B2, const float* bias2, int nsplit,
                  const void* B3, const float* bias3, int nsplit2,
                  float* Cf, int ldc, short* Cb, int ldcb,
                  short* Ct, int ldct, int nsplitT,
                  int M, int N, int K)
{
    dim3 g((N + 63) / 64, (M + 63) / 64);
    if (!tb) {
        if (epi == 0)      mgemm_k<0, false><<<g, 256, 0, st>>>(A, lda, B, ldb, bias, B2, bias2, nsplit, B3, bias3, nsplit2, Cf, ldc, Cb, ldcb, Ct, ldct, nsplitT, M, N, K);
        else if (epi == 1) mgemm_k<1, false><<<g, 256, 0, st>>>(A, lda, B, ldb, bias, B2, bias2, nsplit, B3, bias3, nsplit2, Cf, ldc, Cb, ldcb, Ct, ldct, nsplitT, M, N, K);
        else               mgemm_k<2, false><<<g, 256, 0, st>>>(A, lda, B, ldb, bias, B2, bias2, nsplit, B3, bias3, nsplit2, Cf, ldc, Cb, ldcb, Ct, ldct, nsplitT, M, N, K);
    } else {
        if (epi == 0)      mgemm_k<0, true><<<g, 256, 0, st>>>(A, lda, B, ldb, bias, B2, bias2, nsplit, B3, bias3, nsplit2, Cf, ldc, Cb, ldcb, Ct, ldct, nsplitT, M, N, K);
        else if (epi == 1) mgemm_k<1, true><<<g, 256, 0, st>>>(A, lda, B, ldb, bias, B2, bias2, nsplit, B3, bias3, nsplit2, Cf, ldc, Cb, ldcb, Ct, ldct, nsplitT, M, N, K);
        else               mgemm_k<2, true><<<g, 256, 0, st>>>(A, lda, B, ldb, bias, B2, bias2, nsplit, B3, bias3, nsplit2, Cf, ldc, Cb, ldcb, Ct, ldct, nsplitT, M, N, K);
    }
}

extern "C" void kernel_launch(void* const* d_in, const int* in_sizes, int n_in,
                              void* d_out, int out_size, void* d_ws, size_t ws_size,
                              hipStream_t stream)
{
    const float* doc_emb   = (const float*)d_in[0];
    const float* labels    = (const float*)d_in[1];
    const float* label_emb = (const float*)d_in[2];
    const float* label_adj = (const float*)d_in[3];
    const float* w_gcn3    = (const float*)d_in[4];
    const float* w_gcn5    = (const float*)d_in[5];
    const float* w_ll1     = (const float*)d_in[6];
    const float* b_ll1     = (const float*)d_in[7];
    const float* w_ll2     = (const float*)d_in[8];
    const float* b_ll2     = (const float*)d_in[9];
    const float* w_lin     = (const float*)d_in[10];
    const float* b_lin     = (const float*)d_in[11];
    const float* conv_w    = (const float*)d_in[12];
    const float* conv_b    = (const float*)d_in[13];
    const float* w_lin1    = (const float*)d_in[14];
    const float* b_lin1    = (const float*)d_in[15];

    float* out = (float*)d_out;   // [B*L] + [1]

    char* p = (char*)d_ws;
    auto alloc = [&](size_t bytes) { void* r = p; p += (bytes + 15) & ~(size_t)15; return r; };
    short* wkg       = (short*)alloc(WROWS * WP * 2);
    short* adj_bf    = (short*)alloc(200 * APAD * 2);
    short* E2_bf     = (short*)alloc(200 * 768 * 2);
    short* le_cat_bf = (short*)alloc(200 * 1536 * 2);   // [le | d_le]
    short* qkh_bf    = (short*)alloc(200 * 2304 * 2);   // [q | k | H]
    short* Ht        = (short*)alloc(768 * 256 * 2);    // H^T, K-pitch 256
    float* Amat      = (float*)alloc(200 * 200 * 4);
    short* Anorm_bf  = (short*)alloc(200 * APAD * 2);
    float* le_out_f  = (float*)alloc(200 * 768 * 4);
    short* le_out_bf = (short*)alloc(200 * 768 * 2);
    short* doc_nb    = (short*)alloc((size_t)BB * SS * DD * 2);
    short* wlab      = (short*)alloc((size_t)BB * SS * LL * 2);
    float* gatev     = (float*)alloc(BB * SS * 4);
    float* hpart     = (float*)alloc(BB * 8 * DD * 4);

    // prep (conv weights kappa-order + bias fold, adj pad)
    prep_k<<<(WROWS * WP + LL * APAD + 255) / 256, 256, 0, stream>>>(
        conv_w, conv_b, label_adj, wkg, adj_bf);
    // E2 = adj @ emb   [200,768] K=200
    mgemm(stream, 0, false, adj_bf, APAD, label_emb, DD, nullptr,
          nullptr, nullptr, BIGN, nullptr, nullptr, BIGN,
          nullptr, 0, E2_bf, DD, nullptr, 0, BIGN, LL, DD, LL);
    // le = leaky(E2 @ W3) -> bf16 le_cat[:, :768]
    mgemm(stream, 1, false, E2_bf, DD, w_gcn3, DD, nullptr,
          nullptr, nullptr, BIGN, nullptr, nullptr, BIGN,
          nullptr, 0, le_cat_bf, 1536, nullptr, 0, BIGN, LL, DD, DD);
    // [q|k|H] = le @ [w_ll1|w_ll2|w_gcn5] + [b1|b2|0]  N=2304; H also -> Ht^T
    mgemm(stream, 0, false, le_cat_bf, 1536, w_ll1, DD, b_ll1,
          w_ll2, b_ll2, DD, w_gcn5, nullptr, 2 * DD,
          nullptr, 0, qkh_bf, 2304, Ht, 256, 2 * DD, LL, 3 * DD, DD);
    // A = sigmoid(q @ k^T)  [200,200] K=768
    mgemm(stream, 2, true, qkh_bf, 2304, qkh_bf + DD, 2304, nullptr,
          nullptr, nullptr, BIGN, nullptr, nullptr, BIGN,
          Amat, LL, nullptr, 0, nullptr, 0, BIGN, LL, LL, DD);
    // fused colsum + rsqrt + normalized adjacency
    ca_k<<<LL, 256, 0, stream>>>(Amat, Anorm_bf);
    // d_le = leaky(Anorm @ H)  K=200 via Ht (B^T layout) -> le_cat[:, 768:]
    mgemm(stream, 1, true, Anorm_bf, APAD, Ht, 256, nullptr,
          nullptr, nullptr, BIGN, nullptr, nullptr, BIGN,
          nullptr, 0, le_cat_bf + DD, 1536, nullptr, 0, BIGN, LL, DD, LL);
    // le_out = le_cat @ w_lin + b_lin   K=1536
    mgemm(stream, 0, false, le_cat_bf, 1536, w_lin, DD, b_lin,
          nullptr, nullptr, BIGN, nullptr, nullptr, BIGN,
          le_out_f, DD, nullptr, 0, nullptr, 0, BIGN, LL, DD, 2 * DD);
    // l1 normalize over L -> bf16
    l1n_k<<<96, 256, 0, stream>>>(le_out_f, le_out_bf);
    // doc l1 norm (fused denom + convert) -> bf16 doc
    docnorm_k<<<dim3(12, 8), 256, 0, stream>>>(doc_emb, doc_nb);
    // wla = doc_n @ le_out^T   [4096,200] K=768 -> bf16 output
    mgemm(stream, 0, true, doc_nb, DD, le_out_bf, DD, nullptr,
          nullptr, nullptr, BIGN, nullptr, nullptr, BIGN,
          nullptr, 0, wlab, LL, nullptr, 0, BIGN, BB * SS, LL, DD);
    // conv + max + tanh (bf16 input, branch-free MFMA body)
    (void)hipFuncSetAttribute((const void*)conv_max_k,
                              hipFuncAttributeMaxDynamicSharedMemorySize, 116736);
    conv_max_k<<<1024, 512, 116736, stream>>>(wlab, wkg, gatev);
    // h_enc partials (bf16 doc_nb) + final + loss
    henc_part_k<<<dim3(12, 8, 8), 256, 0, stream>>>(doc_nb, gatev, hpart);
    final2_k<<<BB, 256, 0, stream>>>(hpart, w_lin1, b_lin1, out);
    loss_k<<<1, 256, 0, stream>>>(out, labels, out + BB * LL);
}